// Round 1
// baseline (454.840 us; speedup 1.0000x reference)
//
#include <hip/hip_runtime.h>
#include <cstdint>
#include <cstddef>

// Problem constants (from reference): B=32, N=2048, L=128, D=1024, V=32000
#define BATCH 32
#define NROW  2048
#define LTOK  128
#define DDIM  1024

// Tile config: one block handles one (batch, 128-row) tile against all 128 tokens.
#define BM    128
#define BK    64
#define LDST  72   // LDS row stride in bf16 elems: 64 + 8 pad (144 B, keeps 16B align, 2-way banks only)

typedef short s8v  __attribute__((ext_vector_type(8)));
typedef float f4v  __attribute__((ext_vector_type(4)));

__device__ __forceinline__ short f2bf(float f) {
    union { float f; uint32_t u; } c; c.f = f;
    uint32_t u = c.u + 0x7FFFu + ((c.u >> 16) & 1u);   // round-to-nearest-even
    return (short)(u >> 16);
}

__device__ __forceinline__ float sq8(const float4& a, const float4& b) {
    return a.x*a.x + a.y*a.y + a.z*a.z + a.w*a.w
         + b.x*b.x + b.y*b.y + b.z*b.z + b.w*b.w;
}

__device__ __forceinline__ s8v pack8(const float4& a, const float4& b) {
    s8v v;
    v[0] = f2bf(a.x); v[1] = f2bf(a.y); v[2] = f2bf(a.z); v[3] = f2bf(a.w);
    v[4] = f2bf(b.x); v[5] = f2bf(b.y); v[6] = f2bf(b.z); v[7] = f2bf(b.w);
    return v;
}

__global__ __launch_bounds__(256, 2)
void cdist_min_mean_kernel(const float* __restrict__ X,     // [B, N, D]
                           const int*   __restrict__ tok,   // [B, L]
                           const float* __restrict__ E,     // [V, D]
                           float* __restrict__ out)         // [1]
{
    __shared__ __align__(16) short Xs[BM * LDST];
    __shared__ __align__(16) short Ys[LTOK * LDST];
    __shared__ float x2s[BM];
    __shared__ float y2s[LTOK];
    __shared__ float rowmin[BM * 2];
    __shared__ float wsum[4];

    const int tid  = threadIdx.x;
    const int lane = tid & 63;
    const int wid  = tid >> 6;
    const int grp  = tid >> 3;   // 0..31  (staging row group)
    const int sub  = tid & 7;    // 0..7   (staging col: sub*8 floats)

    const int b       = blockIdx.y;
    const int rowBase = blockIdx.x * BM;

    const float* Xg = X + ((size_t)b * NROW + rowBase) * DDIM;

    // Per-thread fixed row pointers (4 rows each for X-tile and Y-tile)
    const float* xp[4];
    const float* yp[4];
#pragma unroll
    for (int i = 0; i < 4; ++i) {
        int r = grp + 32 * i;                  // tile row 0..127
        xp[i] = Xg + (size_t)r * DDIM + sub * 8;
        int t = tok[b * LTOK + r];
        yp[i] = E + (size_t)t * DDIM + sub * 8;
    }

    f4v acc[4][4];
#pragma unroll
    for (int mi = 0; mi < 4; ++mi)
#pragma unroll
        for (int ni = 0; ni < 4; ++ni)
            acc[mi][ni] = (f4v){0.f, 0.f, 0.f, 0.f};

    float xacc[4] = {0.f, 0.f, 0.f, 0.f};
    float yacc[4] = {0.f, 0.f, 0.f, 0.f};

    const int quad = lane >> 4;
    const int l15  = lane & 15;
    const int wm   = wid >> 1;   // wave row offset /64
    const int wn   = wid & 1;    // wave col offset /64

    for (int k0 = 0; k0 < DDIM; k0 += BK) {
        // Issue global loads before the barrier (overlap with previous MFMA phase)
        float4 xa[4], xb[4], ya[4], yb[4];
#pragma unroll
        for (int i = 0; i < 4; ++i) {
            xa[i] = *(const float4*)(xp[i] + k0);
            xb[i] = *(const float4*)(xp[i] + k0 + 4);
            ya[i] = *(const float4*)(yp[i] + k0);
            yb[i] = *(const float4*)(yp[i] + k0 + 4);
        }
        __syncthreads();   // previous iter's LDS reads complete
#pragma unroll
        for (int i = 0; i < 4; ++i) {
            int r = grp + 32 * i;
            xacc[i] += sq8(xa[i], xb[i]);
            yacc[i] += sq8(ya[i], yb[i]);
            *(s8v*)&Xs[r * LDST + sub * 8] = pack8(xa[i], xb[i]);
            *(s8v*)&Ys[r * LDST + sub * 8] = pack8(ya[i], yb[i]);
        }
        __syncthreads();   // tiles staged

#pragma unroll
        for (int ks = 0; ks < BK; ks += 32) {
            s8v af[4], bfr[4];
#pragma unroll
            for (int mi = 0; mi < 4; ++mi)
                af[mi] = *(const s8v*)&Xs[(wm * 64 + mi * 16 + l15) * LDST + ks + quad * 8];
#pragma unroll
            for (int ni = 0; ni < 4; ++ni)
                bfr[ni] = *(const s8v*)&Ys[(wn * 64 + ni * 16 + l15) * LDST + ks + quad * 8];
#pragma unroll
            for (int mi = 0; mi < 4; ++mi)
#pragma unroll
                for (int ni = 0; ni < 4; ++ni)
                    acc[mi][ni] = __builtin_amdgcn_mfma_f32_16x16x32_bf16(
                        af[mi], bfr[ni], acc[mi][ni], 0, 0, 0);
        }
    }

    // Reduce x2/y2: 8 threads (contiguous lanes) share each row
#pragma unroll
    for (int i = 0; i < 4; ++i) {
        float s = xacc[i];
        s += __shfl_xor(s, 1); s += __shfl_xor(s, 2); s += __shfl_xor(s, 4);
        if ((lane & 7) == 0) x2s[grp + 32 * i] = s;
        float t2 = yacc[i];
        t2 += __shfl_xor(t2, 1); t2 += __shfl_xor(t2, 2); t2 += __shfl_xor(t2, 4);
        if ((lane & 7) == 0) y2s[grp + 32 * i] = t2;
    }
    __syncthreads();

    // Epilogue: per output row, min over cols of (y2[col] - 2*S).
    // C/D layout (verified): col = lane&15, row = quad*4 + reg.
    float y2r[4];
#pragma unroll
    for (int ni = 0; ni < 4; ++ni)
        y2r[ni] = y2s[wn * 64 + ni * 16 + l15];

#pragma unroll
    for (int mi = 0; mi < 4; ++mi) {
#pragma unroll
        for (int j = 0; j < 4; ++j) {
            float m = y2r[0] - 2.f * acc[mi][0][j];
            m = fminf(m, y2r[1] - 2.f * acc[mi][1][j]);
            m = fminf(m, y2r[2] - 2.f * acc[mi][2][j]);
            m = fminf(m, y2r[3] - 2.f * acc[mi][3][j]);
            // min over the 16 cols held by this quad's 16 lanes
            m = fminf(m, __shfl_xor(m, 1));
            m = fminf(m, __shfl_xor(m, 2));
            m = fminf(m, __shfl_xor(m, 4));
            m = fminf(m, __shfl_xor(m, 8));
            if (l15 == 0)
                rowmin[(wm * 64 + mi * 16 + quad * 4 + j) * 2 + wn] = m;
        }
    }
    __syncthreads();

    // Combine the two wave-columns, apply x2, sqrt, and block-sum
    float part = 0.f;
    if (tid < BM) {
        float m = fminf(rowmin[tid * 2], rowmin[tid * 2 + 1]);
        part = sqrtf(fmaxf(x2s[tid] + m, 0.f));
    }
#pragma unroll
    for (int s = 1; s < 64; s <<= 1) part += __shfl_xor(part, s);
    if (lane == 0) wsum[wid] = part;
    __syncthreads();
    if (tid == 0) {
        float tot = (wsum[0] + wsum[1] + wsum[2] + wsum[3])
                  * (1.0f / (float)(BATCH * NROW));
        atomicAdd(out, tot);
    }
}

extern "C" void kernel_launch(void* const* d_in, const int* in_sizes, int n_in,
                              void* d_out, int out_size, void* d_ws, size_t ws_size,
                              hipStream_t stream) {
    const float* X   = (const float*)d_in[0];  // image_features [B,N,D] fp32
    const int*   tok = (const int*)d_in[1];    // token_ids [B,L] int
    const float* E   = (const float*)d_in[2];  // emb_table [V,D] fp32
    float* out = (float*)d_out;

    // d_out is poisoned before every timed launch — zero it, then atomically accumulate.
    hipMemsetAsync(out, 0, sizeof(float), stream);

    dim3 grid(NROW / BM, BATCH, 1);   // 16 x 32 = 512 blocks (2/CU)
    dim3 block(256, 1, 1);
    cdist_min_mean_kernel<<<grid, block, 0, stream>>>(X, tok, E, out);
}

// Round 2
// 440.120 us; speedup vs baseline: 1.0334x; 1.0334x over previous
//
#include <hip/hip_runtime.h>
#include <cstdint>
#include <cstddef>

// Problem constants: B=32, N=2048, L=128, D=1024, V=32000
#define BATCH 32
#define NROW  2048
#define LTOK  128
#define DDIM  1024

#define BM    128
#define BK    64
#define LDST  72   // padded X-tile LDS row stride (bf16 elems): 144 B -> 2-way banks only (free)

typedef short s8v  __attribute__((ext_vector_type(8)));
typedef float f4v  __attribute__((ext_vector_type(4)));

// Truncation-pack two fp32 -> packed bf16 pair in ONE v_perm_b32.
// perm(a=hi, b=lo, sel): sel bytes 0-3 index lo, 4-7 index hi.
// result: low16 = lo bytes[3:2] (bf16-trunc of lo), high16 = hi bytes[3:2].
__device__ __forceinline__ uint32_t pk2(float lo, float hi) {
    return __builtin_amdgcn_perm(__float_as_uint(hi), __float_as_uint(lo), 0x07060302u);
}

// ---------------- Pre-pass: gather + bf16-convert targets, compute y2 ----------------
__global__ __launch_bounds__(256)
void prep_y(const int*   __restrict__ tok,   // [B, L]
            const float* __restrict__ E,     // [V, D]
            uint32_t*    __restrict__ Ybf,   // [B*L*D/2] packed bf16 pairs
            float*       __restrict__ y2)    // [B*L]
{
    const int l = blockIdx.x, b = blockIdx.y;
    const int tid = threadIdx.x;               // 256 threads, 4 floats each
    const int t = tok[b * LTOK + l];
    const float4 v = ((const float4*)(E + (size_t)t * DDIM))[tid];
    float s = v.x*v.x + v.y*v.y + v.z*v.z + v.w*v.w;
    uint2 p; p.x = pk2(v.x, v.y); p.y = pk2(v.z, v.w);
    ((uint2*)(Ybf + ((size_t)(b * LTOK + l) * DDIM) / 2))[tid] = p;
#pragma unroll
    for (int o = 1; o < 64; o <<= 1) s += __shfl_xor(s, o);
    __shared__ float ws4[4];
    if ((tid & 63) == 0) ws4[tid >> 6] = s;
    __syncthreads();
    if (tid == 0) y2[b * LTOK + l] = ws4[0] + ws4[1] + ws4[2] + ws4[3];
}

// ---------------- Main kernel ----------------
__global__ __launch_bounds__(256, 2)
void cdist_min_mean_kernel(const float* __restrict__ X,     // [B, N, D] fp32
                           const short* __restrict__ Ybf,   // [B, L, D] bf16 (pre-gathered)
                           const float* __restrict__ y2g,   // [B, L]
                           float* __restrict__ out)
{
    __shared__ __align__(16) short Xs[BM * LDST];
    __shared__ __align__(16) short Ys[LTOK * 64];   // unpadded, XOR-swizzled chunks
    __shared__ float x2s[BM];
    __shared__ float rowmin[BM * 2];
    __shared__ float wsum[4];

    const int tid  = threadIdx.x;
    const int lane = tid & 63;
    const int wid  = tid >> 6;
    const int grp  = tid >> 3;   // 0..31 staging row group
    const int sub  = tid & 7;    // staging col: sub*8 floats

    const int b       = blockIdx.y;
    const int rowBase = blockIdx.x * BM;

    const float* Xg = X + ((size_t)b * NROW + rowBase) * DDIM;

    // X row pointers (4 rows/thread)
    const float* xp[4];
#pragma unroll
    for (int i = 0; i < 4; ++i)
        xp[i] = Xg + (size_t)(grp + 32 * i) * DDIM + sub * 8;

    // Y DMA source pointers: LDS slot c=it*256+tid holds row=c>>3,
    // stored-chunk=c&7, whose DATA is source-chunk (c&7)^(row&7)  (XOR swizzle).
    const short* yg[4];
#pragma unroll
    for (int it = 0; it < 4; ++it) {
        int c   = it * 256 + tid;
        int row = c >> 3;
        int chs = (c & 7) ^ (row & 7);
        yg[it] = Ybf + (size_t)(b * LTOK + row) * DDIM + chs * 8;
    }

    f4v acc[4][4];
#pragma unroll
    for (int mi = 0; mi < 4; ++mi)
#pragma unroll
        for (int ni = 0; ni < 4; ++ni)
            acc[mi][ni] = (f4v){0.f, 0.f, 0.f, 0.f};

    float xacc[4] = {0.f, 0.f, 0.f, 0.f};

    const int quad = lane >> 4;
    const int l15  = lane & 15;
    const int wm   = wid >> 1;
    const int wn   = wid & 1;

    for (int k0 = 0; k0 < DDIM; k0 += BK) {
        // X loads into regs (issue early; overlap prev iter's MFMA + barrier wait)
        float4 xa[4], xb[4];
#pragma unroll
        for (int i = 0; i < 4; ++i) {
            xa[i] = *(const float4*)(xp[i] + k0);
            xb[i] = *(const float4*)(xp[i] + k0 + 4);
        }
        __syncthreads();   // all waves done reading prev tiles

        // Y: async DMA global->LDS, 16B/lane, LDS base wave-uniform
#pragma unroll
        for (int it = 0; it < 4; ++it)
            __builtin_amdgcn_global_load_lds(
                (const __attribute__((address_space(1))) void*)(yg[it] + k0),
                (__attribute__((address_space(3))) void*)&Ys[(it * 256 + (wid << 6)) * 8],
                16, 0, 0);

        // X: fp32 sumsq (exact) + trunc-pack to bf16 LDS
#pragma unroll
        for (int i = 0; i < 4; ++i) {
            const float4 a = xa[i], c4 = xb[i];
            xacc[i] += a.x*a.x + a.y*a.y + a.z*a.z + a.w*a.w
                     + c4.x*c4.x + c4.y*c4.y + c4.z*c4.z + c4.w*c4.w;
            uint4 p;
            p.x = pk2(a.x, a.y);  p.y = pk2(a.z, a.w);
            p.z = pk2(c4.x, c4.y); p.w = pk2(c4.z, c4.w);
            *(uint4*)&Xs[(grp + 32 * i) * LDST + sub * 8] = p;
        }
        __syncthreads();   // vmcnt(0) drain covers the Y DMA + LDS stores

#pragma unroll
        for (int ks = 0; ks < BK; ks += 32) {
            s8v af[4], bfr[4];
#pragma unroll
            for (int mi = 0; mi < 4; ++mi)
                af[mi] = *(const s8v*)&Xs[(wm * 64 + mi * 16 + l15) * LDST + ks + quad * 8];
#pragma unroll
            for (int ni = 0; ni < 4; ++ni) {
                int brow = wn * 64 + ni * 16 + l15;
                int ch   = ((ks >> 3) + quad) ^ (brow & 7);
                bfr[ni]  = *(const s8v*)&Ys[brow * 64 + ch * 8];
            }
#pragma unroll
            for (int mi = 0; mi < 4; ++mi)
#pragma unroll
                for (int ni = 0; ni < 4; ++ni)
                    acc[mi][ni] = __builtin_amdgcn_mfma_f32_16x16x32_bf16(
                        af[mi], bfr[ni], acc[mi][ni], 0, 0, 0);
        }
    }

    // x2: 8 consecutive lanes share each row
#pragma unroll
    for (int i = 0; i < 4; ++i) {
        float s = xacc[i];
        s += __shfl_xor(s, 1); s += __shfl_xor(s, 2); s += __shfl_xor(s, 4);
        if ((lane & 7) == 0) x2s[grp + 32 * i] = s;
    }
    __syncthreads();

    // Epilogue: per row, min over cols of (y2[col] - 2*S).  C/D: col=lane&15, row=quad*4+reg.
    float y2r[4];
#pragma unroll
    for (int ni = 0; ni < 4; ++ni)
        y2r[ni] = y2g[b * LTOK + wn * 64 + ni * 16 + l15];

#pragma unroll
    for (int mi = 0; mi < 4; ++mi) {
#pragma unroll
        for (int j = 0; j < 4; ++j) {
            float m = y2r[0] - 2.f * acc[mi][0][j];
            m = fminf(m, y2r[1] - 2.f * acc[mi][1][j]);
            m = fminf(m, y2r[2] - 2.f * acc[mi][2][j]);
            m = fminf(m, y2r[3] - 2.f * acc[mi][3][j]);
            m = fminf(m, __shfl_xor(m, 1));
            m = fminf(m, __shfl_xor(m, 2));
            m = fminf(m, __shfl_xor(m, 4));
            m = fminf(m, __shfl_xor(m, 8));
            if (l15 == 0)
                rowmin[(wm * 64 + mi * 16 + quad * 4 + j) * 2 + wn] = m;
        }
    }
    __syncthreads();

    float part = 0.f;
    if (tid < BM) {
        float m = fminf(rowmin[tid * 2], rowmin[tid * 2 + 1]);
        part = sqrtf(fmaxf(x2s[tid] + m, 0.f));
    }
#pragma unroll
    for (int s = 1; s < 64; s <<= 1) part += __shfl_xor(part, s);
    if (lane == 0) wsum[wid] = part;
    __syncthreads();
    if (tid == 0) {
        float tot = (wsum[0] + wsum[1] + wsum[2] + wsum[3])
                  * (1.0f / (float)(BATCH * NROW));
        atomicAdd(out, tot);
    }
}

extern "C" void kernel_launch(void* const* d_in, const int* in_sizes, int n_in,
                              void* d_out, int out_size, void* d_ws, size_t ws_size,
                              hipStream_t stream) {
    const float* X   = (const float*)d_in[0];  // image_features [B,N,D] fp32
    const int*   tok = (const int*)d_in[1];    // token_ids [B,L] int32
    const float* E   = (const float*)d_in[2];  // emb_table [V,D] fp32
    float* out = (float*)d_out;

    // ws layout: [0, 8MB) Ybf bf16, [8MB, 8MB+16KB) y2 fp32
    uint32_t* Ybf = (uint32_t*)d_ws;
    float*    y2  = (float*)((char*)d_ws + (size_t)BATCH * LTOK * DDIM * 2);

    hipMemsetAsync(out, 0, sizeof(float), stream);

    dim3 pgrid(LTOK, BATCH, 1);
    prep_y<<<pgrid, 256, 0, stream>>>(tok, E, Ybf, y2);

    dim3 grid(NROW / BM, BATCH, 1);   // 16 x 32 = 512 blocks
    cdist_min_mean_kernel<<<grid, 256, 0, stream>>>(X, (const short*)Ybf, y2, out);
}